// Round 17
// baseline (148.703 us; speedup 1.0000x reference)
//
#include <hip/hip_runtime.h>
#include <hip/hip_fp16.h>

#define LDIM 256
#define NDIM 256
#define DZC  128
#define HN   4
#define DHD  32
#define DCC  128
#define MROWS (LDIM*NDIM)

typedef _Float16 f16;
typedef _Float16 f16x2 __attribute__((ext_vector_type(2)));
typedef _Float16 f16x4 __attribute__((ext_vector_type(4)));
typedef _Float16 f16x8 __attribute__((ext_vector_type(8)));
typedef __fp16   h16x2 __attribute__((ext_vector_type(2)));
typedef float    f32x4 __attribute__((ext_vector_type(4)));

#define SCAL 0.17677669529663687f      // 1/sqrt(32)
#define CEXP -0.011270992135622957f    // -log2(e)/128
#define CPRE 0.2550340490960039f       // SCAL * log2(e)

__device__ inline f16x2 pkrtz(float a, float b){
  h16x2 r = __builtin_amdgcn_cvt_pkrtz(a, b);
  union { h16x2 h; f16x2 f; } u; u.h = r;
  return u.f;
}

// ---------------- K0b: pack W^T f16 — w16[p][col][k] = W_p[k][col] ----------------
__global__ __launch_bounds__(256) void k0b_pack(
    const float* __restrict__ Wq, const float* __restrict__ Wk,
    const float* __restrict__ Wv, const float* __restrict__ Wg,
    const float* __restrict__ Wo, f16* __restrict__ w16)
{
  const float* Ws[5] = {Wq, Wk, Wv, Wg, Wo};
  const int tid = blockIdx.x * 256 + threadIdx.x;
  const int p = tid >> 14, rem = tid & 16383;
  const int col = rem >> 7, k = rem & 127;
  w16[tid] = (f16)Ws[p][k*128 + col];
}

// ---------------- K1: LN + Q/K/V/Gate via MFMA — register-LN, no LDS ----------------
// Wave = 16 rows x one projection; block = 4 waves over same 16 rows; grid 4096.
// Lane (m,g) loads z[row m][ks*32+g*8..] (the MFMA B-frag distribution) directly;
// row LN-reduce via shfl_xor(16/32) over the 4 g-lanes. acc[8]=32 regs (vs 128)
// -> 3-4 waves/SIMD. Single phase: no barrier, compiler pipelines everything.
__global__ __launch_bounds__(256, 2) void k1_ln_qkvg(
    const float* __restrict__ z, const float* __restrict__ lng, const float* __restrict__ lnb,
    const f16* __restrict__ w16,
    const float* __restrict__ bq, const float* __restrict__ bk,
    const float* __restrict__ bv, const float* __restrict__ bg,
    f16* __restrict__ qb, f16* __restrict__ kbuf,
    f16* __restrict__ vbuf, f16* __restrict__ gateb)
{
  const int t = threadIdx.x;
  const int w = t >> 6, lane = t & 63;
  const int m = lane & 15, g = lane >> 4;
  const int row = blockIdx.x * 16 + m;
  const float* zr = z + (size_t)row*DZC + g*8;

  // ---- load this lane's 32 z values (cols ks*32 + g*8 + e) ----
  float4 zv[4][2];
  #pragma unroll
  for (int ks = 0; ks < 4; ++ks) {
    zv[ks][0] = *reinterpret_cast<const float4*>(zr + ks*32);
    zv[ks][1] = *reinterpret_cast<const float4*>(zr + ks*32 + 4);
  }

  // ---- LN stats: partial sums, then reduce across the 4 g-lanes of this row ----
  float s = 0.f, sq = 0.f;
  #pragma unroll
  for (int ks = 0; ks < 4; ++ks)
    #pragma unroll
    for (int h = 0; h < 2; ++h) {
      const float4 v4 = zv[ks][h];
      s  += (v4.x + v4.y) + (v4.z + v4.w);
      sq += (v4.x*v4.x + v4.y*v4.y) + (v4.z*v4.z + v4.w*v4.w);
    }
  s  += __shfl_xor(s, 16);  sq += __shfl_xor(sq, 16);
  s  += __shfl_xor(s, 32);  sq += __shfl_xor(sq, 32);
  const float mu   = s * (1.f/DZC);
  const float var  = sq * (1.f/DZC) - mu*mu;
  const float rstd = rsqrtf(var + 1e-5f);

  // ---- normalize + scale/shift -> B-fragments (f16x8 per ks) ----
  f16x8 bf[4];
  #pragma unroll
  for (int ks = 0; ks < 4; ++ks) {
    const float4 g0 = *reinterpret_cast<const float4*>(lng + ks*32 + g*8);
    const float4 g1 = *reinterpret_cast<const float4*>(lng + ks*32 + g*8 + 4);
    const float4 b0 = *reinterpret_cast<const float4*>(lnb + ks*32 + g*8);
    const float4 b1 = *reinterpret_cast<const float4*>(lnb + ks*32 + g*8 + 4);
    const float gv[8] = {g0.x,g0.y,g0.z,g0.w,g1.x,g1.y,g1.z,g1.w};
    const float bv[8] = {b0.x,b0.y,b0.z,b0.w,b1.x,b1.y,b1.z,b1.w};
    const float zvv[8] = {zv[ks][0].x,zv[ks][0].y,zv[ks][0].z,zv[ks][0].w,
                          zv[ks][1].x,zv[ks][1].y,zv[ks][1].z,zv[ks][1].w};
    f16x8 o;
    #pragma unroll
    for (int e = 0; e < 8; ++e)
      o[e] = (f16)((zvv[e]-mu)*rstd*gv[e] + bv[e]);
    bf[ks] = o;
  }

  // ---- GEMM: acc[jt] (16 rows x 128 cols, lane m = row, regs = 4 cols) ----
  const f16* wp = w16 + w*16384;
  f32x4 acc[8];
  #pragma unroll
  for (int jt=0;jt<8;++jt) acc[jt] = (f32x4){0.f,0.f,0.f,0.f};

  #pragma unroll
  for (int ks = 0; ks < 4; ++ks) {
    f16x8 af[8];
    #pragma unroll
    for (int jt=0;jt<8;++jt)
      af[jt] = *reinterpret_cast<const f16x8*>(wp + (jt*16+m)*128 + ks*32 + g*8);
    #pragma unroll
    for (int jt=0;jt<8;++jt)
      acc[jt] = __builtin_amdgcn_mfma_f32_16x16x32_f16(af[jt], bf[ks], acc[jt], 0,0,0);
  }

  // ---- epilogue: bias (+sigmoid for gate), one row base, 8 static stores ----
  const float* bsp = (w==0) ? bq : (w==1) ? bk : (w==2) ? bv : bg;
  f16* ob = (w==0) ? qb : (w==1) ? kbuf : (w==2) ? vbuf : gateb;
  f16* orow = ob + (size_t)row*DCC;
  #pragma unroll
  for (int jt=0;jt<8;++jt) {
    const float4 bias = *reinterpret_cast<const float4*>(bsp + jt*16 + g*4);
    const float bb[4] = {bias.x, bias.y, bias.z, bias.w};
    f16x4 o;
    #pragma unroll
    for (int r=0;r<4;++r) {
      float v = acc[jt][r] + bb[r];
      if (w == 3) v = 1.f/(1.f + __expf(-v));
      o[r] = (f16)v;
    }
    *reinterpret_cast<f16x4*>(orow + jt*16 + g*4) = o;
  }
}

// ---------------- K2: fused attention + output projection (R15, verified) ----------------
__global__ __launch_bounds__(256, 2) void k2_attn(
    const f16* __restrict__ qb, const f16* __restrict__ kbuf,
    const f16* __restrict__ vbuf, const f16* __restrict__ gateb,
    const float* __restrict__ dist, const f16* __restrict__ wo16,
    const float* __restrict__ bo, float* __restrict__ out)
{
  __shared__ f16 vt[4*32*256];   // 64 KB V^T; reused as zc[128][132] in epilogue
  __shared__ float cfl[64*64];   // 16 KB f32 coef tile (64 rows)
  const int t = threadIdx.x;
  const int w = t >> 6, lane = t & 63;
  const int m = lane & 15, g = lane >> 4;
  const int orig = blockIdx.x;
  const int swz = (orig & 7)*64 + (orig >> 3);   // bijective XCD swizzle (512%8==0)
  const int l = swz >> 1, half = swz & 1;
  const int r0 = half*128;
  const int lrow0 = l*NDIM;

  { // build VT from row-major vbuf
    #pragma unroll
    for (int hh = 0; hh < 4; ++hh) {
      const f16* vr = vbuf + (size_t)(lrow0 + t)*DCC + hh*DHD;
      #pragma unroll
      for (int p = 0; p < 4; ++p) {
        f16x8 v = *reinterpret_cast<const f16x8*>(vr + p*8);
        #pragma unroll
        for (int e = 0; e < 8; ++e) {
          const int c = p*8 + e;
          vt[hh*8192 + c*256 + (((t>>2) ^ (c&15))*4) + (t&3)] = v[e];
        }
      }
    }
  }

  f16x8 aq[8];
  #pragma unroll
  for (int it = 0; it < 8; ++it)
    aq[it] = *reinterpret_cast<const f16x8*>(
        qb + (size_t)(lrow0 + r0 + it*16 + m)*DCC + w*DHD + g*8);

  f32x4 o[8][2];
  float rs[8];
  #pragma unroll
  for (int it = 0; it < 8; ++it) {
    o[it][0] = (f32x4){0.f,0.f,0.f,0.f};
    o[it][1] = (f32x4){0.f,0.f,0.f,0.f};
    rs[it] = 0.f;
  }

  const float* drow = dist + (size_t)l*(NDIM*NDIM);
  const int prow[4] = { (0*256+t) >> 4, (1*256+t) >> 4, (2*256+t) >> 4, (3*256+t) >> 4 };
  const int pf4  = t & 15;

  // prologue: issue stage-0 (jc=0, rh=0) dist loads into regs
  float4 pf[4];
  #pragma unroll
  for (int p = 0; p < 4; ++p)
    pf[p] = *reinterpret_cast<const float4*>(
        drow + (size_t)(r0 + prow[p])*NDIM + pf4*4);

  __syncthreads();   // VT build complete before any wave reads vt

  const f16* vth = vt + w*8192;

  #pragma unroll 1
  for (int jc = 0; jc < 4; ++jc) {
    f16x8 kf[4];
    #pragma unroll
    for (int jt = 0; jt < 4; ++jt)
      kf[jt] = *reinterpret_cast<const f16x8*>(
          kbuf + (size_t)(lrow0 + jc*64 + jt*16 + m)*DCC + w*DHD + g*8);

    f16x8 bvv[2][2];
    #pragma unroll
    for (int kc = 0; kc < 2; ++kc)
      #pragma unroll
      for (int ct = 0; ct < 2; ++ct) {
        const int c = ct*16 + m;
        const f16x4 lo = *reinterpret_cast<const f16x4*>(
            vth + c*256 + (((jc*16 + (2*kc+0)*4 + g) ^ m) * 4));
        const f16x4 hi = *reinterpret_cast<const f16x4*>(
            vth + c*256 + (((jc*16 + (2*kc+1)*4 + g) ^ m) * 4));
        f16x8 bb;
        #pragma unroll
        for (int e = 0; e < 4; ++e) { bb[e] = lo[e]; bb[4+e] = hi[e]; }
        bvv[kc][ct] = bb;
      }

    #pragma unroll
    for (int rh = 0; rh < 2; ++rh) {
      __syncthreads();   // prior cfl reads complete
      float4 d0 = pf[0], d1 = pf[1], d2 = pf[2], d3 = pf[3];
      { // issue NEXT stage's loads — in flight through compute
        const int si1 = jc*2 + rh + 1;
        const int sic = (si1 > 7) ? 7 : si1;
        const int jn = sic >> 1, rn = sic & 1;
        #pragma unroll
        for (int p = 0; p < 4; ++p)
          pf[p] = *reinterpret_cast<const float4*>(
              drow + (size_t)(r0 + rn*64 + prow[p])*NDIM + jn*64 + pf4*4);
      }
      {
        const float4 dd[4] = {d0, d1, d2, d3};
        #pragma unroll
        for (int p = 0; p < 4; ++p) {
          const int row = prow[p];
          float4 cf4;
          cf4.x = CPRE * exp2f(dd[p].x*dd[p].x*CEXP);
          cf4.y = CPRE * exp2f(dd[p].y*dd[p].y*CEXP);
          cf4.z = CPRE * exp2f(dd[p].z*dd[p].z*CEXP);
          cf4.w = CPRE * exp2f(dd[p].w*dd[p].w*CEXP);
          *reinterpret_cast<float4*>(cfl + row*64 + ((pf4 ^ (row & 15))*4)) = cf4;
        }
      }
      __syncthreads();

      #pragma unroll
      for (int itl = 0; itl < 4; ++itl) {
        const int it = rh*4 + itl;
        const int lr = itl*16 + m;
        float4 cl[4];
        #pragma unroll
        for (int jt = 0; jt < 4; ++jt)
          cl[jt] = *reinterpret_cast<const float4*>(
              cfl + lr*64 + (((jt*4 + g) ^ m)*4));

        f32x4 s[4];
        #pragma unroll
        for (int jt = 0; jt < 4; ++jt)
          s[jt] = __builtin_amdgcn_mfma_f32_16x16x32_f16(
              kf[jt], aq[it], (f32x4){0.f,0.f,0.f,0.f}, 0, 0, 0);

        f16x2 pk[4][2];
        #pragma unroll
        for (int jt = 0; jt < 4; ++jt) {
          const float p0 = exp2f(s[jt][0] * cl[jt].x);
          const float p1 = exp2f(s[jt][1] * cl[jt].y);
          const float p2 = exp2f(s[jt][2] * cl[jt].z);
          const float p3 = exp2f(s[jt][3] * cl[jt].w);
          rs[it] += (p0 + p1) + (p2 + p3);
          pk[jt][0] = pkrtz(p0, p1);
          pk[jt][1] = pkrtz(p2, p3);
        }

        #pragma unroll
        for (int kc = 0; kc < 2; ++kc) {
          const f16x4 x = __builtin_shufflevector(pk[2*kc  ][0], pk[2*kc  ][1], 0,1,2,3);
          const f16x4 y = __builtin_shufflevector(pk[2*kc+1][0], pk[2*kc+1][1], 0,1,2,3);
          const f16x8 ap = __builtin_shufflevector(x, y, 0,1,2,3,4,5,6,7);
          o[it][0] = __builtin_amdgcn_mfma_f32_16x16x32_f16(ap, bvv[kc][0], o[it][0], 0, 0, 0);
          o[it][1] = __builtin_amdgcn_mfma_f32_16x16x32_f16(ap, bvv[kc][1], o[it][1], 0, 0, 0);
        }
      }
    }
  }

  float rinv[8];
  #pragma unroll
  for (int it = 0; it < 8; ++it) {
    float v = rs[it];
    v += __shfl_xor(v, 16);
    v += __shfl_xor(v, 32);
    rinv[it] = 1.f / v;
  }

  // ---- fused epilogue: z_com -> LDS, then out = (zc*gate) @ Wo + bo ----
  __syncthreads();   // all waves done reading vt (jc=3 bvv)
  f16* zc = vt;      // [128][132]
  #pragma unroll
  for (int it = 0; it < 8; ++it)
    #pragma unroll
    for (int r = 0; r < 4; ++r) {
      const float rr = __shfl(rinv[it], (lane & 48) + g*4 + r);
      const int lrow = it*16 + g*4 + r;
      #pragma unroll
      for (int ct = 0; ct < 2; ++ct)
        zc[lrow*132 + w*DHD + ct*16 + m] = (f16)(o[it][ct][r] * rr);
    }
  __syncthreads();

  f32x4 acc2[2][8];
  #pragma unroll
  for (int it2=0;it2<2;++it2)
    #pragma unroll
    for (int jt=0;jt<8;++jt) acc2[it2][jt] = (f32x4){0.f,0.f,0.f,0.f};

  #pragma unroll
  for (int ks = 0; ks < 4; ++ks) {
    f16x8 af[8];
    #pragma unroll
    for (int jt=0;jt<8;++jt)
      af[jt] = *reinterpret_cast<const f16x8*>(wo16 + (jt*16+m)*128 + ks*32 + g*8);
    f16x8 bf[2];
    #pragma unroll
    for (int it2 = 0; it2 < 2; ++it2) {
      const int lrow = w*32 + it2*16 + m;
      const f16x4 b0 = *reinterpret_cast<const f16x4*>(zc + lrow*132 + ks*32 + g*8);
      const f16x4 b1 = *reinterpret_cast<const f16x4*>(zc + lrow*132 + ks*32 + g*8 + 4);
      const f16x8 zf = __builtin_shufflevector(b0, b1, 0,1,2,3,4,5,6,7);
      const f16x8 gf = *reinterpret_cast<const f16x8*>(
          gateb + (size_t)(lrow0 + r0 + lrow)*DCC + ks*32 + g*8);
      bf[it2] = zf * gf;
    }
    #pragma unroll
    for (int it2=0;it2<2;++it2)
      #pragma unroll
      for (int jt=0;jt<8;++jt)
        acc2[it2][jt] = __builtin_amdgcn_mfma_f32_16x16x32_f16(af[jt], bf[it2], acc2[it2][jt], 0,0,0);
  }

  #pragma unroll
  for (int it2 = 0; it2 < 2; ++it2) {
    const size_t grow = (size_t)(lrow0 + r0 + w*32 + it2*16 + m);
    #pragma unroll
    for (int jt = 0; jt < 8; ++jt) {
      const float4 bias = *reinterpret_cast<const float4*>(bo + jt*16 + g*4);
      float4 ov;
      ov.x = acc2[it2][jt][0] + bias.x;
      ov.y = acc2[it2][jt][1] + bias.y;
      ov.z = acc2[it2][jt][2] + bias.z;
      ov.w = acc2[it2][jt][3] + bias.w;
      *reinterpret_cast<float4*>(out + grow*DZC + jt*16 + g*4) = ov;
    }
  }
}

extern "C" void kernel_launch(void* const* d_in, const int* in_sizes, int n_in,
                              void* d_out, int out_size, void* d_ws, size_t ws_size,
                              hipStream_t stream) {
  const float* z    = (const float*)d_in[0];
  const float* dist = (const float*)d_in[1];
  const float* lng  = (const float*)d_in[2];
  const float* lnb  = (const float*)d_in[3];
  const float* Wq   = (const float*)d_in[4];
  const float* bq   = (const float*)d_in[5];
  const float* Wk   = (const float*)d_in[6];
  const float* bk   = (const float*)d_in[7];
  const float* Wv   = (const float*)d_in[8];
  const float* bv   = (const float*)d_in[9];
  const float* Wg   = (const float*)d_in[10];
  const float* bg   = (const float*)d_in[11];
  const float* Wo   = (const float*)d_in[12];
  const float* bo   = (const float*)d_in[13];
  float* out = (float*)d_out;

  const size_t elems = (size_t)MROWS * DCC;  // 8,388,608
  f16* qb    = (f16*)d_ws;
  f16* kbuf  = qb    + elems;
  f16* vbuf  = kbuf  + elems;
  f16* gateb = vbuf  + elems;
  f16* w16   = gateb + elems;   // 5*16384 halves; total ws ≈ 67 MB

  k0b_pack<<<320, 256, 0, stream>>>(Wq, Wk, Wv, Wg, Wo, w16);
  k1_ln_qkvg<<<MROWS/16, 256, 0, stream>>>(z, lng, lnb, w16, bq, bk, bv, bg,
                                           qb, kbuf, vbuf, gateb);
  k2_attn<<<LDIM*2, 256, 0, stream>>>(qb, kbuf, vbuf, gateb, dist,
                                      w16 + 4*16384, bo, out);
}

// Round 18
// 94.006 us; speedup vs baseline: 1.5818x; 1.5818x over previous
//
#include <hip/hip_runtime.h>
#include <hip/hip_fp16.h>

#define LDIM 256
#define NDIM 256
#define DZC  128
#define HN   4
#define DHD  32
#define DCC  128
#define MROWS (LDIM*NDIM)

typedef _Float16 f16;
typedef _Float16 f16x2 __attribute__((ext_vector_type(2)));
typedef _Float16 f16x4 __attribute__((ext_vector_type(4)));
typedef _Float16 f16x8 __attribute__((ext_vector_type(8)));
typedef __fp16   h16x2 __attribute__((ext_vector_type(2)));
typedef float    f32x4 __attribute__((ext_vector_type(4)));

#define SCAL 0.17677669529663687f      // 1/sqrt(32)
#define CEXP -0.011270992135622957f    // -log2(e)/128
#define CPRE 0.2550340490960039f       // SCAL * log2(e)

__device__ inline f16x2 pkrtz(float a, float b){
  h16x2 r = __builtin_amdgcn_cvt_pkrtz(a, b);
  union { h16x2 h; f16x2 f; } u; u.h = r;
  return u.f;
}

// ---------------- K0b: pack W^T f16 in MFMA-FRAGMENT order ----------------
// wfrag[p][((jt*4+ks)*64 + lane)*8 + e] = W_p[k][col],
//   col = jt*16 + (lane&15), k = ks*32 + (lane>>4)*8 + e.
// A-fragment loads become one contiguous 1KB wave transaction (vs 64 lines).
__global__ __launch_bounds__(256) void k0b_pack(
    const float* __restrict__ Wq, const float* __restrict__ Wk,
    const float* __restrict__ Wv, const float* __restrict__ Wg,
    const float* __restrict__ Wo, f16* __restrict__ w16)
{
  const float* Ws[5] = {Wq, Wk, Wv, Wg, Wo};
  const int tid = blockIdx.x * 256 + threadIdx.x;
  const int p = tid >> 14, rem = tid & 16383;
  const int e = rem & 7, lane = (rem >> 3) & 63, ksjt = rem >> 9;
  const int ks = ksjt & 3, jt = ksjt >> 2;
  const int col = jt*16 + (lane & 15);
  const int k   = ks*32 + (lane >> 4)*8 + e;
  w16[tid] = (f16)Ws[p][k*128 + col];
}

// ---------------- K1: LN + Q/K/V/Gate via MFMA (R15 structure + frag weights) ----------------
__global__ __launch_bounds__(256, 2) void k1_ln_qkvg(
    const float* __restrict__ z, const float* __restrict__ lng, const float* __restrict__ lnb,
    const f16* __restrict__ w16,
    const float* __restrict__ bq, const float* __restrict__ bk,
    const float* __restrict__ bv, const float* __restrict__ bg,
    f16* __restrict__ qb, f16* __restrict__ kbuf,
    f16* __restrict__ vbuf, f16* __restrict__ gateb)
{
  __shared__ f16 zl[64*128];   // 16 KB
  const int t = threadIdx.x;
  const int w = t >> 6, lane = t & 63;
  const int m = lane & 15, g = lane >> 4;
  const int row0 = blockIdx.x * 64;

  {
    const int r = t >> 2, part = t & 3;
    const float* zr = z + (size_t)(row0 + r)*DZC + part*32;
    float vals[32];
    float s = 0.f, sq = 0.f;
    #pragma unroll
    for (int i = 0; i < 8; ++i) {
      float4 v4 = reinterpret_cast<const float4*>(zr)[i];
      vals[i*4+0]=v4.x; vals[i*4+1]=v4.y; vals[i*4+2]=v4.z; vals[i*4+3]=v4.w;
      s  += v4.x+v4.y+v4.z+v4.w;
      sq += v4.x*v4.x + v4.y*v4.y + v4.z*v4.z + v4.w*v4.w;
    }
    s  += __shfl_xor(s, 1);  sq += __shfl_xor(sq, 1);
    s  += __shfl_xor(s, 2);  sq += __shfl_xor(sq, 2);
    const float mu  = s * (1.f/DZC);
    const float var = sq * (1.f/DZC) - mu*mu;
    const float rstd = rsqrtf(var + 1e-5f);
    const float* gg = lng + part*32;
    const float* bb = lnb + part*32;
    #pragma unroll
    for (int i = 0; i < 4; ++i) {
      f16x8 o;
      #pragma unroll
      for (int e = 0; e < 8; ++e)
        o[e] = (f16)((vals[i*8+e]-mu)*rstd*gg[i*8+e] + bb[i*8+e]);
      *reinterpret_cast<f16x8*>(zl + r*128 + (((part*4+i) ^ (r&7))*8)) = o;
    }
  }
  __syncthreads();

  const f16* wp = w16 + w*16384;
  f32x4 acc[4][8];
  #pragma unroll
  for (int it=0;it<4;++it)
    #pragma unroll
    for (int jt=0;jt<8;++jt) acc[it][jt] = (f32x4){0.f,0.f,0.f,0.f};

  #pragma unroll
  for (int ks = 0; ks < 4; ++ks) {
    f16x8 af[8];
    #pragma unroll
    for (int jt=0;jt<8;++jt)
      af[jt] = *reinterpret_cast<const f16x8*>(wp + ((jt*4+ks)*64 + lane)*8);
    f16x8 bf[4];
    #pragma unroll
    for (int it=0;it<4;++it)
      bf[it] = *reinterpret_cast<const f16x8*>(zl + (it*16+m)*128 + (((ks*4+g) ^ (m&7))*8));
    #pragma unroll
    for (int it=0;it<4;++it)
      #pragma unroll
      for (int jt=0;jt<8;++jt)
        acc[it][jt] = __builtin_amdgcn_mfma_f32_16x16x32_f16(af[jt], bf[it], acc[it][jt], 0,0,0);
  }

  const float* bsp = (w==0) ? bq : (w==1) ? bk : (w==2) ? bv : bg;
  float4 bias[8];
  #pragma unroll
  for (int jt=0;jt<8;++jt)
    bias[jt] = *reinterpret_cast<const float4*>(bsp + jt*16 + g*4);

  f16* ob = (w==0) ? qb : (w==1) ? kbuf : (w==2) ? vbuf : gateb;
  #pragma unroll
  for (int it=0;it<4;++it) {
    f16* orow = ob + (size_t)(row0 + it*16 + m)*DCC;
    #pragma unroll
    for (int jt=0;jt<8;++jt) {
      f16x4 o;
      #pragma unroll
      for (int r=0;r<4;++r) {
        float v = acc[it][jt][r] + ((const float*)&bias[jt])[r];
        if (w == 3) v = 1.f/(1.f + __expf(-v));
        o[r] = (f16)v;
      }
      *reinterpret_cast<f16x4*>(orow + jt*16 + g*4) = o;
    }
  }
}

// ---------------- K2: fused attention + output projection ----------------
__global__ __launch_bounds__(256, 2) void k2_attn(
    const f16* __restrict__ qb, const f16* __restrict__ kbuf,
    const f16* __restrict__ vbuf, const f16* __restrict__ gateb,
    const float* __restrict__ dist, const f16* __restrict__ wo16,
    const float* __restrict__ bo, float* __restrict__ out)
{
  __shared__ f16 vt[4*32*256];   // 64 KB V^T; reused as zc[128][132] in epilogue
  __shared__ float cfl[64*64];   // 16 KB f32 coef tile (64 rows)
  const int t = threadIdx.x;
  const int w = t >> 6, lane = t & 63;
  const int m = lane & 15, g = lane >> 4;
  const int orig = blockIdx.x;
  const int swz = (orig & 7)*64 + (orig >> 3);   // bijective XCD swizzle (512%8==0)
  const int l = swz >> 1, half = swz & 1;
  const int r0 = half*128;
  const int lrow0 = l*NDIM;

  { // build VT from row-major vbuf
    #pragma unroll
    for (int hh = 0; hh < 4; ++hh) {
      const f16* vr = vbuf + (size_t)(lrow0 + t)*DCC + hh*DHD;
      #pragma unroll
      for (int p = 0; p < 4; ++p) {
        f16x8 v = *reinterpret_cast<const f16x8*>(vr + p*8);
        #pragma unroll
        for (int e = 0; e < 8; ++e) {
          const int c = p*8 + e;
          vt[hh*8192 + c*256 + (((t>>2) ^ (c&15))*4) + (t&3)] = v[e];
        }
      }
    }
  }

  f16x8 aq[8];
  #pragma unroll
  for (int it = 0; it < 8; ++it)
    aq[it] = *reinterpret_cast<const f16x8*>(
        qb + (size_t)(lrow0 + r0 + it*16 + m)*DCC + w*DHD + g*8);

  f32x4 o[8][2];
  float rs[8];
  #pragma unroll
  for (int it = 0; it < 8; ++it) {
    o[it][0] = (f32x4){0.f,0.f,0.f,0.f};
    o[it][1] = (f32x4){0.f,0.f,0.f,0.f};
    rs[it] = 0.f;
  }

  const float* drow = dist + (size_t)l*(NDIM*NDIM);
  const int prow[4] = { (0*256+t) >> 4, (1*256+t) >> 4, (2*256+t) >> 4, (3*256+t) >> 4 };
  const int pf4  = t & 15;

  // prologue: issue stage-0 (jc=0, rh=0) dist loads into regs
  float4 pf[4];
  #pragma unroll
  for (int p = 0; p < 4; ++p)
    pf[p] = *reinterpret_cast<const float4*>(
        drow + (size_t)(r0 + prow[p])*NDIM + pf4*4);

  __syncthreads();   // VT build complete before any wave reads vt

  const f16* vth = vt + w*8192;

  #pragma unroll 1
  for (int jc = 0; jc < 4; ++jc) {
    f16x8 kf[4];
    #pragma unroll
    for (int jt = 0; jt < 4; ++jt)
      kf[jt] = *reinterpret_cast<const f16x8*>(
          kbuf + (size_t)(lrow0 + jc*64 + jt*16 + m)*DCC + w*DHD + g*8);

    f16x8 bvv[2][2];
    #pragma unroll
    for (int kc = 0; kc < 2; ++kc)
      #pragma unroll
      for (int ct = 0; ct < 2; ++ct) {
        const int c = ct*16 + m;
        const f16x4 lo = *reinterpret_cast<const f16x4*>(
            vth + c*256 + (((jc*16 + (2*kc+0)*4 + g) ^ m) * 4));
        const f16x4 hi = *reinterpret_cast<const f16x4*>(
            vth + c*256 + (((jc*16 + (2*kc+1)*4 + g) ^ m) * 4));
        f16x8 bb;
        #pragma unroll
        for (int e = 0; e < 4; ++e) { bb[e] = lo[e]; bb[4+e] = hi[e]; }
        bvv[kc][ct] = bb;
      }

    #pragma unroll
    for (int rh = 0; rh < 2; ++rh) {
      __syncthreads();   // prior cfl reads complete
      float4 d0 = pf[0], d1 = pf[1], d2 = pf[2], d3 = pf[3];
      { // issue NEXT stage's loads — in flight through compute
        const int si1 = jc*2 + rh + 1;
        const int sic = (si1 > 7) ? 7 : si1;
        const int jn = sic >> 1, rn = sic & 1;
        #pragma unroll
        for (int p = 0; p < 4; ++p)
          pf[p] = *reinterpret_cast<const float4*>(
              drow + (size_t)(r0 + rn*64 + prow[p])*NDIM + jn*64 + pf4*4);
      }
      {
        const float4 dd[4] = {d0, d1, d2, d3};
        #pragma unroll
        for (int p = 0; p < 4; ++p) {
          const int row = prow[p];
          float4 cf4;
          cf4.x = CPRE * exp2f(dd[p].x*dd[p].x*CEXP);
          cf4.y = CPRE * exp2f(dd[p].y*dd[p].y*CEXP);
          cf4.z = CPRE * exp2f(dd[p].z*dd[p].z*CEXP);
          cf4.w = CPRE * exp2f(dd[p].w*dd[p].w*CEXP);
          *reinterpret_cast<float4*>(cfl + row*64 + ((pf4 ^ (row & 15))*4)) = cf4;
        }
      }
      __syncthreads();

      #pragma unroll
      for (int itl = 0; itl < 4; ++itl) {
        const int it = rh*4 + itl;
        const int lr = itl*16 + m;
        float4 cl[4];
        #pragma unroll
        for (int jt = 0; jt < 4; ++jt)
          cl[jt] = *reinterpret_cast<const float4*>(
              cfl + lr*64 + (((jt*4 + g) ^ m)*4));

        f32x4 s[4];
        #pragma unroll
        for (int jt = 0; jt < 4; ++jt)
          s[jt] = __builtin_amdgcn_mfma_f32_16x16x32_f16(
              kf[jt], aq[it], (f32x4){0.f,0.f,0.f,0.f}, 0, 0, 0);

        f16x2 pk[4][2];
        #pragma unroll
        for (int jt = 0; jt < 4; ++jt) {
          const float p0 = exp2f(s[jt][0] * cl[jt].x);
          const float p1 = exp2f(s[jt][1] * cl[jt].y);
          const float p2 = exp2f(s[jt][2] * cl[jt].z);
          const float p3 = exp2f(s[jt][3] * cl[jt].w);
          rs[it] += (p0 + p1) + (p2 + p3);
          pk[jt][0] = pkrtz(p0, p1);
          pk[jt][1] = pkrtz(p2, p3);
        }

        #pragma unroll
        for (int kc = 0; kc < 2; ++kc) {
          const f16x4 x = __builtin_shufflevector(pk[2*kc  ][0], pk[2*kc  ][1], 0,1,2,3);
          const f16x4 y = __builtin_shufflevector(pk[2*kc+1][0], pk[2*kc+1][1], 0,1,2,3);
          const f16x8 ap = __builtin_shufflevector(x, y, 0,1,2,3,4,5,6,7);
          o[it][0] = __builtin_amdgcn_mfma_f32_16x16x32_f16(ap, bvv[kc][0], o[it][0], 0, 0, 0);
          o[it][1] = __builtin_amdgcn_mfma_f32_16x16x32_f16(ap, bvv[kc][1], o[it][1], 0, 0, 0);
        }
      }
    }
  }

  float rinv[8];
  #pragma unroll
  for (int it = 0; it < 8; ++it) {
    float v = rs[it];
    v += __shfl_xor(v, 16);
    v += __shfl_xor(v, 32);
    rinv[it] = 1.f / v;
  }

  // ---- fused epilogue: z_com -> LDS, then out = (zc*gate) @ Wo + bo ----
  __syncthreads();   // all waves done reading vt (jc=3 bvv)
  f16* zc = vt;      // [128][132]
  #pragma unroll
  for (int it = 0; it < 8; ++it)
    #pragma unroll
    for (int r = 0; r < 4; ++r) {
      const float rr = __shfl(rinv[it], (lane & 48) + g*4 + r);
      const int lrow = it*16 + g*4 + r;
      #pragma unroll
      for (int ct = 0; ct < 2; ++ct)
        zc[lrow*132 + w*DHD + ct*16 + m] = (f16)(o[it][ct][r] * rr);
    }
  __syncthreads();

  f32x4 acc2[2][8];
  #pragma unroll
  for (int it2=0;it2<2;++it2)
    #pragma unroll
    for (int jt=0;jt<8;++jt) acc2[it2][jt] = (f32x4){0.f,0.f,0.f,0.f};

  #pragma unroll
  for (int ks = 0; ks < 4; ++ks) {
    f16x8 af[8];
    #pragma unroll
    for (int jt=0;jt<8;++jt)
      af[jt] = *reinterpret_cast<const f16x8*>(wo16 + ((jt*4+ks)*64 + lane)*8);
    f16x8 bf[2];
    #pragma unroll
    for (int it2 = 0; it2 < 2; ++it2) {
      const int lrow = w*32 + it2*16 + m;
      const f16x4 b0 = *reinterpret_cast<const f16x4*>(zc + lrow*132 + ks*32 + g*8);
      const f16x4 b1 = *reinterpret_cast<const f16x4*>(zc + lrow*132 + ks*32 + g*8 + 4);
      const f16x8 zf = __builtin_shufflevector(b0, b1, 0,1,2,3,4,5,6,7);
      const f16x8 gf = *reinterpret_cast<const f16x8*>(
          gateb + (size_t)(lrow0 + r0 + lrow)*DCC + ks*32 + g*8);
      bf[it2] = zf * gf;
    }
    #pragma unroll
    for (int it2=0;it2<2;++it2)
      #pragma unroll
      for (int jt=0;jt<8;++jt)
        acc2[it2][jt] = __builtin_amdgcn_mfma_f32_16x16x32_f16(af[jt], bf[it2], acc2[it2][jt], 0,0,0);
  }

  #pragma unroll
  for (int it2 = 0; it2 < 2; ++it2) {
    const size_t grow = (size_t)(lrow0 + r0 + w*32 + it2*16 + m);
    #pragma unroll
    for (int jt = 0; jt < 8; ++jt) {
      const float4 bias = *reinterpret_cast<const float4*>(bo + jt*16 + g*4);
      float4 ov;
      ov.x = acc2[it2][jt][0] + bias.x;
      ov.y = acc2[it2][jt][1] + bias.y;
      ov.z = acc2[it2][jt][2] + bias.z;
      ov.w = acc2[it2][jt][3] + bias.w;
      *reinterpret_cast<float4*>(out + grow*DZC + jt*16 + g*4) = ov;
    }
  }
}

extern "C" void kernel_launch(void* const* d_in, const int* in_sizes, int n_in,
                              void* d_out, int out_size, void* d_ws, size_t ws_size,
                              hipStream_t stream) {
  const float* z    = (const float*)d_in[0];
  const float* dist = (const float*)d_in[1];
  const float* lng  = (const float*)d_in[2];
  const float* lnb  = (const float*)d_in[3];
  const float* Wq   = (const float*)d_in[4];
  const float* bq   = (const float*)d_in[5];
  const float* Wk   = (const float*)d_in[6];
  const float* bk   = (const float*)d_in[7];
  const float* Wv   = (const float*)d_in[8];
  const float* bv   = (const float*)d_in[9];
  const float* Wg   = (const float*)d_in[10];
  const float* bg   = (const float*)d_in[11];
  const float* Wo   = (const float*)d_in[12];
  const float* bo   = (const float*)d_in[13];
  float* out = (float*)d_out;

  const size_t elems = (size_t)MROWS * DCC;  // 8,388,608
  f16* qb    = (f16*)d_ws;
  f16* kbuf  = qb    + elems;
  f16* vbuf  = kbuf  + elems;
  f16* gateb = vbuf  + elems;
  f16* w16   = gateb + elems;   // 5*16384 halves; total ws ≈ 67 MB

  k0b_pack<<<320, 256, 0, stream>>>(Wq, Wk, Wv, Wg, Wo, w16);
  k1_ln_qkvg<<<MROWS/64, 256, 0, stream>>>(z, lng, lnb, w16, bq, bk, bv, bg,
                                           qb, kbuf, vbuf, gateb);
  k2_attn<<<LDIM*2, 256, 0, stream>>>(qb, kbuf, vbuf, gateb, dist,
                                      w16 + 4*16384, bo, out);
}

// Round 19
// 86.486 us; speedup vs baseline: 1.7194x; 1.0870x over previous
//
#include <hip/hip_runtime.h>
#include <hip/hip_fp16.h>

#define LDIM 256
#define NDIM 256
#define DZC  128
#define HN   4
#define DHD  32
#define DCC  128
#define MROWS (LDIM*NDIM)

typedef _Float16 f16;
typedef _Float16 f16x2 __attribute__((ext_vector_type(2)));
typedef _Float16 f16x4 __attribute__((ext_vector_type(4)));
typedef _Float16 f16x8 __attribute__((ext_vector_type(8)));
typedef __fp16   h16x2 __attribute__((ext_vector_type(2)));
typedef float    f32x4 __attribute__((ext_vector_type(4)));

#define SCAL 0.17677669529663687f      // 1/sqrt(32)
#define CEXP -0.011270992135622957f    // -log2(e)/128
#define CPRE 0.2550340490960039f       // SCAL * log2(e)

extern "C" __device__ _Float16 __ocml_exp2_f16(_Float16);  // -> v_exp_f16

__device__ inline f16x2 pkrtz(float a, float b){
  h16x2 r = __builtin_amdgcn_cvt_pkrtz(a, b);
  union { h16x2 h; f16x2 f; } u; u.h = r;
  return u.f;
}

// ---------------- K0b: pack W^T f16 in MFMA-FRAGMENT order ----------------
// wfrag[p][((jt*4+ks)*64 + lane)*8 + e] = W_p[k][col],
//   col = jt*16 + (lane&15), k = ks*32 + (lane>>4)*8 + e.
__global__ __launch_bounds__(256) void k0b_pack(
    const float* __restrict__ Wq, const float* __restrict__ Wk,
    const float* __restrict__ Wv, const float* __restrict__ Wg,
    const float* __restrict__ Wo, f16* __restrict__ w16)
{
  const float* Ws[5] = {Wq, Wk, Wv, Wg, Wo};
  const int tid = blockIdx.x * 256 + threadIdx.x;
  const int p = tid >> 14, rem = tid & 16383;
  const int e = rem & 7, lane = (rem >> 3) & 63, ksjt = rem >> 9;
  const int ks = ksjt & 3, jt = ksjt >> 2;
  const int col = jt*16 + (lane & 15);
  const int k   = ks*32 + (lane >> 4)*8 + e;
  w16[tid] = (f16)Ws[p][k*128 + col];
}

// ---------------- K1: LN + Q/K/V/Gate via MFMA (R17, verified) ----------------
__global__ __launch_bounds__(256, 2) void k1_ln_qkvg(
    const float* __restrict__ z, const float* __restrict__ lng, const float* __restrict__ lnb,
    const f16* __restrict__ w16,
    const float* __restrict__ bq, const float* __restrict__ bk,
    const float* __restrict__ bv, const float* __restrict__ bg,
    f16* __restrict__ qb, f16* __restrict__ kbuf,
    f16* __restrict__ vbuf, f16* __restrict__ gateb)
{
  __shared__ f16 zl[64*128];   // 16 KB
  const int t = threadIdx.x;
  const int w = t >> 6, lane = t & 63;
  const int m = lane & 15, g = lane >> 4;
  const int row0 = blockIdx.x * 64;

  {
    const int r = t >> 2, part = t & 3;
    const float* zr = z + (size_t)(row0 + r)*DZC + part*32;
    float vals[32];
    float s = 0.f, sq = 0.f;
    #pragma unroll
    for (int i = 0; i < 8; ++i) {
      float4 v4 = reinterpret_cast<const float4*>(zr)[i];
      vals[i*4+0]=v4.x; vals[i*4+1]=v4.y; vals[i*4+2]=v4.z; vals[i*4+3]=v4.w;
      s  += v4.x+v4.y+v4.z+v4.w;
      sq += v4.x*v4.x + v4.y*v4.y + v4.z*v4.z + v4.w*v4.w;
    }
    s  += __shfl_xor(s, 1);  sq += __shfl_xor(sq, 1);
    s  += __shfl_xor(s, 2);  sq += __shfl_xor(sq, 2);
    const float mu  = s * (1.f/DZC);
    const float var = sq * (1.f/DZC) - mu*mu;
    const float rstd = rsqrtf(var + 1e-5f);
    const float* gg = lng + part*32;
    const float* bb = lnb + part*32;
    #pragma unroll
    for (int i = 0; i < 4; ++i) {
      f16x8 o;
      #pragma unroll
      for (int e = 0; e < 8; ++e)
        o[e] = (f16)((vals[i*8+e]-mu)*rstd*gg[i*8+e] + bb[i*8+e]);
      *reinterpret_cast<f16x8*>(zl + r*128 + (((part*4+i) ^ (r&7))*8)) = o;
    }
  }
  __syncthreads();

  const f16* wp = w16 + w*16384;
  f32x4 acc[4][8];
  #pragma unroll
  for (int it=0;it<4;++it)
    #pragma unroll
    for (int jt=0;jt<8;++jt) acc[it][jt] = (f32x4){0.f,0.f,0.f,0.f};

  #pragma unroll
  for (int ks = 0; ks < 4; ++ks) {
    f16x8 af[8];
    #pragma unroll
    for (int jt=0;jt<8;++jt)
      af[jt] = *reinterpret_cast<const f16x8*>(wp + ((jt*4+ks)*64 + lane)*8);
    f16x8 bf[4];
    #pragma unroll
    for (int it=0;it<4;++it)
      bf[it] = *reinterpret_cast<const f16x8*>(zl + (it*16+m)*128 + (((ks*4+g) ^ (m&7))*8));
    #pragma unroll
    for (int it=0;it<4;++it)
      #pragma unroll
      for (int jt=0;jt<8;++jt)
        acc[it][jt] = __builtin_amdgcn_mfma_f32_16x16x32_f16(af[jt], bf[it], acc[it][jt], 0,0,0);
  }

  const float* bsp = (w==0) ? bq : (w==1) ? bk : (w==2) ? bv : bg;
  float4 bias[8];
  #pragma unroll
  for (int jt=0;jt<8;++jt)
    bias[jt] = *reinterpret_cast<const float4*>(bsp + jt*16 + g*4);

  f16* ob = (w==0) ? qb : (w==1) ? kbuf : (w==2) ? vbuf : gateb;
  #pragma unroll
  for (int it=0;it<4;++it) {
    f16* orow = ob + (size_t)(row0 + it*16 + m)*DCC;
    #pragma unroll
    for (int jt=0;jt<8;++jt) {
      f16x4 o;
      #pragma unroll
      for (int r=0;r<4;++r) {
        float v = acc[it][jt][r] + ((const float*)&bias[jt])[r];
        if (w == 3) v = 1.f/(1.f + __expf(-v));
        o[r] = (f16)v;
      }
      *reinterpret_cast<f16x4*>(orow + jt*16 + g*4) = o;
    }
  }
}

// ---------------- K2: fused attention + out-proj; f16 dbuf cfl + packed glue ----------------
__global__ __launch_bounds__(256, 2) void k2_attn(
    const f16* __restrict__ qb, const f16* __restrict__ kbuf,
    const f16* __restrict__ vbuf, const f16* __restrict__ gateb,
    const float* __restrict__ dist, const f16* __restrict__ wo16,
    const float* __restrict__ bo, float* __restrict__ out)
{
  __shared__ f16 vt[4*32*256];   // 64 KB V^T; reused as zc[128][132] in epilogue
  __shared__ f16 cfl[2][64*64];  // 16 KB f16 coef tiles, double-buffered (buf = rh)
  const int t = threadIdx.x;
  const int w = t >> 6, lane = t & 63;
  const int m = lane & 15, g = lane >> 4;
  const int orig = blockIdx.x;
  const int swz = (orig & 7)*64 + (orig >> 3);   // bijective XCD swizzle (512%8==0)
  const int l = swz >> 1, half = swz & 1;
  const int r0 = half*128;
  const int lrow0 = l*NDIM;

  { // build VT from row-major vbuf
    #pragma unroll
    for (int hh = 0; hh < 4; ++hh) {
      const f16* vr = vbuf + (size_t)(lrow0 + t)*DCC + hh*DHD;
      #pragma unroll
      for (int p = 0; p < 4; ++p) {
        f16x8 v = *reinterpret_cast<const f16x8*>(vr + p*8);
        #pragma unroll
        for (int e = 0; e < 8; ++e) {
          const int c = p*8 + e;
          vt[hh*8192 + c*256 + (((t>>2) ^ (c&15))*4) + (t&3)] = v[e];
        }
      }
    }
  }

  f16x8 aq[8];
  #pragma unroll
  for (int it = 0; it < 8; ++it)
    aq[it] = *reinterpret_cast<const f16x8*>(
        qb + (size_t)(lrow0 + r0 + it*16 + m)*DCC + w*DHD + g*8);

  f32x4 o[8][2];
  float rs[8];
  #pragma unroll
  for (int it = 0; it < 8; ++it) {
    o[it][0] = (f32x4){0.f,0.f,0.f,0.f};
    o[it][1] = (f32x4){0.f,0.f,0.f,0.f};
    rs[it] = 0.f;
  }

  const float* drow = dist + (size_t)l*(NDIM*NDIM);
  const int prow[4] = { (0*256+t) >> 4, (1*256+t) >> 4, (2*256+t) >> 4, (3*256+t) >> 4 };
  const int pf4  = t & 15;

  // prologue: issue stage-0 (jc=0, rh=0) dist loads into regs
  float4 pf[4];
  #pragma unroll
  for (int p = 0; p < 4; ++p)
    pf[p] = *reinterpret_cast<const float4*>(
        drow + (size_t)(r0 + prow[p])*NDIM + pf4*4);

  __syncthreads();   // VT build complete before any wave reads vt

  const f16* vth = vt + w*8192;

  #pragma unroll 1
  for (int jc = 0; jc < 4; ++jc) {
    f16x8 kf[4];
    #pragma unroll
    for (int jt = 0; jt < 4; ++jt)
      kf[jt] = *reinterpret_cast<const f16x8*>(
          kbuf + (size_t)(lrow0 + jc*64 + jt*16 + m)*DCC + w*DHD + g*8);

    f16x8 bvv[2][2];
    #pragma unroll
    for (int kc = 0; kc < 2; ++kc)
      #pragma unroll
      for (int ct = 0; ct < 2; ++ct) {
        const int c = ct*16 + m;
        const f16x4 lo = *reinterpret_cast<const f16x4*>(
            vth + c*256 + (((jc*16 + (2*kc+0)*4 + g) ^ m) * 4));
        const f16x4 hi = *reinterpret_cast<const f16x4*>(
            vth + c*256 + (((jc*16 + (2*kc+1)*4 + g) ^ m) * 4));
        f16x8 bb;
        #pragma unroll
        for (int e = 0; e < 4; ++e) { bb[e] = lo[e]; bb[4+e] = hi[e]; }
        bvv[kc][ct] = bb;
      }

    #pragma unroll
    for (int rh = 0; rh < 2; ++rh) {
      f16* cflc = &cfl[rh][0];   // buffer parity = rh (stage index jc*2+rh)
      { // convert + store this stage's prefetched dist -> f16 cfl
        const float4 dd[4] = {pf[0], pf[1], pf[2], pf[3]};
        #pragma unroll
        for (int p = 0; p < 4; ++p) {
          const int row = prow[p];
          const f16x2 a = pkrtz(CPRE*exp2f(dd[p].x*dd[p].x*CEXP),
                                CPRE*exp2f(dd[p].y*dd[p].y*CEXP));
          const f16x2 b = pkrtz(CPRE*exp2f(dd[p].z*dd[p].z*CEXP),
                                CPRE*exp2f(dd[p].w*dd[p].w*CEXP));
          const f16x4 cf = __builtin_shufflevector(a, b, 0,1,2,3);
          *reinterpret_cast<f16x4*>(cflc + row*64 + ((pf4 ^ (row & 15))*4)) = cf;
        }
      }
      { // issue NEXT stage's loads — in flight through compute
        const int si1 = jc*2 + rh + 1;
        const int sic = (si1 > 7) ? 7 : si1;
        const int jn = sic >> 1, rn = sic & 1;
        #pragma unroll
        for (int p = 0; p < 4; ++p)
          pf[p] = *reinterpret_cast<const float4*>(
              drow + (size_t)(r0 + rn*64 + prow[p])*NDIM + jn*64 + pf4*4);
      }
      __syncthreads();   // single barrier: all stores to cfl[rh] visible

      #pragma unroll
      for (int itl = 0; itl < 4; ++itl) {
        const int it = rh*4 + itl;
        const int lr = itl*16 + m;
        f16x4 cl[4];
        #pragma unroll
        for (int jt = 0; jt < 4; ++jt)
          cl[jt] = *reinterpret_cast<const f16x4*>(
              cflc + lr*64 + (((jt*4 + g) ^ m)*4));

        f32x4 s[4];
        #pragma unroll
        for (int jt = 0; jt < 4; ++jt)
          s[jt] = __builtin_amdgcn_mfma_f32_16x16x32_f16(
              kf[jt], aq[it], (f32x4){0.f,0.f,0.f,0.f}, 0, 0, 0);

        // packed-f16 glue: x = f16(s) * cf; p = exp2(x) in f16 (v_exp_f16)
        f16x4 pkk[4];
        #pragma unroll
        for (int jt = 0; jt < 4; ++jt) {
          const f16x2 sl = pkrtz(s[jt][0], s[jt][1]);
          const f16x2 sh = pkrtz(s[jt][2], s[jt][3]);
          const f16x2 cll = __builtin_shufflevector(cl[jt], cl[jt], 0,1);
          const f16x2 clh = __builtin_shufflevector(cl[jt], cl[jt], 2,3);
          const f16x2 xl = sl * cll;
          const f16x2 xh = sh * clh;
          f16x4 pv;
          pv[0] = __ocml_exp2_f16(xl[0]);
          pv[1] = __ocml_exp2_f16(xl[1]);
          pv[2] = __ocml_exp2_f16(xh[0]);
          pv[3] = __ocml_exp2_f16(xh[1]);
          pkk[jt] = pv;
        }
        { // rowsum: packed f16 tree, f32 accumulate (common-mode err cancels)
          const f16x4 ps4 = (pkk[0] + pkk[1]) + (pkk[2] + pkk[3]);
          const f16x2 ps2 = __builtin_shufflevector(ps4, ps4, 0,1)
                          + __builtin_shufflevector(ps4, ps4, 2,3);
          rs[it] += (float)ps2[0] + (float)ps2[1];
        }

        #pragma unroll
        for (int kc = 0; kc < 2; ++kc) {
          const f16x8 ap = __builtin_shufflevector(pkk[2*kc], pkk[2*kc+1],
                                                   0,1,2,3,4,5,6,7);
          o[it][0] = __builtin_amdgcn_mfma_f32_16x16x32_f16(ap, bvv[kc][0], o[it][0], 0, 0, 0);
          o[it][1] = __builtin_amdgcn_mfma_f32_16x16x32_f16(ap, bvv[kc][1], o[it][1], 0, 0, 0);
        }
      }
    }
  }

  float rinv[8];
  #pragma unroll
  for (int it = 0; it < 8; ++it) {
    float v = rs[it];
    v += __shfl_xor(v, 16);
    v += __shfl_xor(v, 32);
    rinv[it] = 1.f / v;
  }

  // ---- fused epilogue: z_com -> LDS, then out = (zc*gate) @ Wo + bo ----
  __syncthreads();   // all waves done reading vt (jc=3 bvv)
  f16* zc = vt;      // [128][132]
  #pragma unroll
  for (int it = 0; it < 8; ++it)
    #pragma unroll
    for (int r = 0; r < 4; ++r) {
      const float rr = __shfl(rinv[it], (lane & 48) + g*4 + r);
      const int lrow = it*16 + g*4 + r;
      #pragma unroll
      for (int ct = 0; ct < 2; ++ct)
        zc[lrow*132 + w*DHD + ct*16 + m] = (f16)(o[it][ct][r] * rr);
    }
  __syncthreads();

  f32x4 acc2[2][8];
  #pragma unroll
  for (int it2=0;it2<2;++it2)
    #pragma unroll
    for (int jt=0;jt<8;++jt) acc2[it2][jt] = (f32x4){0.f,0.f,0.f,0.f};

  #pragma unroll
  for (int ks = 0; ks < 4; ++ks) {
    f16x8 af[8];
    #pragma unroll
    for (int jt=0;jt<8;++jt)
      af[jt] = *reinterpret_cast<const f16x8*>(wo16 + ((jt*4+ks)*64 + lane)*8);
    f16x8 bf[2];
    #pragma unroll
    for (int it2 = 0; it2 < 2; ++it2) {
      const int lrow = w*32 + it2*16 + m;
      const f16x4 b0 = *reinterpret_cast<const f16x4*>(zc + lrow*132 + ks*32 + g*8);
      const f16x4 b1 = *reinterpret_cast<const f16x4*>(zc + lrow*132 + ks*32 + g*8 + 4);
      const f16x8 zf = __builtin_shufflevector(b0, b1, 0,1,2,3,4,5,6,7);
      const f16x8 gf = *reinterpret_cast<const f16x8*>(
          gateb + (size_t)(lrow0 + r0 + lrow)*DCC + ks*32 + g*8);
      bf[it2] = zf * gf;
    }
    #pragma unroll
    for (int it2=0;it2<2;++it2)
      #pragma unroll
      for (int jt=0;jt<8;++jt)
        acc2[it2][jt] = __builtin_amdgcn_mfma_f32_16x16x32_f16(af[jt], bf[it2], acc2[it2][jt], 0,0,0);
  }

  #pragma unroll
  for (int it2 = 0; it2 < 2; ++it2) {
    const size_t grow = (size_t)(lrow0 + r0 + w*32 + it2*16 + m);
    #pragma unroll
    for (int jt = 0; jt < 8; ++jt) {
      const float4 bias = *reinterpret_cast<const float4*>(bo + jt*16 + g*4);
      float4 ov;
      ov.x = acc2[it2][jt][0] + bias.x;
      ov.y = acc2[it2][jt][1] + bias.y;
      ov.z = acc2[it2][jt][2] + bias.z;
      ov.w = acc2[it2][jt][3] + bias.w;
      *reinterpret_cast<float4*>(out + grow*DZC + jt*16 + g*4) = ov;
    }
  }
}

extern "C" void kernel_launch(void* const* d_in, const int* in_sizes, int n_in,
                              void* d_out, int out_size, void* d_ws, size_t ws_size,
                              hipStream_t stream) {
  const float* z    = (const float*)d_in[0];
  const float* dist = (const float*)d_in[1];
  const float* lng  = (const float*)d_in[2];
  const float* lnb  = (const float*)d_in[3];
  const float* Wq   = (const float*)d_in[4];
  const float* bq   = (const float*)d_in[5];
  const float* Wk   = (const float*)d_in[6];
  const float* bk   = (const float*)d_in[7];
  const float* Wv   = (const float*)d_in[8];
  const float* bv   = (const float*)d_in[9];
  const float* Wg   = (const float*)d_in[10];
  const float* bg   = (const float*)d_in[11];
  const float* Wo   = (const float*)d_in[12];
  const float* bo   = (const float*)d_in[13];
  float* out = (float*)d_out;

  const size_t elems = (size_t)MROWS * DCC;  // 8,388,608
  f16* qb    = (f16*)d_ws;
  f16* kbuf  = qb    + elems;
  f16* vbuf  = kbuf  + elems;
  f16* gateb = vbuf  + elems;
  f16* w16   = gateb + elems;   // 5*16384 halves; total ws ≈ 67 MB

  k0b_pack<<<320, 256, 0, stream>>>(Wq, Wk, Wv, Wg, Wo, w16);
  k1_ln_qkvg<<<MROWS/64, 256, 0, stream>>>(z, lng, lnb, w16, bq, bk, bv, bg,
                                           qb, kbuf, vbuf, gateb);
  k2_attn<<<LDIM*2, 256, 0, stream>>>(qb, kbuf, vbuf, gateb, dist,
                                      w16 + 4*16384, bo, out);
}

// Round 20
// 81.739 us; speedup vs baseline: 1.8192x; 1.0581x over previous
//
#include <hip/hip_runtime.h>
#include <hip/hip_fp16.h>

#define LDIM 256
#define NDIM 256
#define DZC  128
#define HN   4
#define DHD  32
#define DCC  128
#define MROWS (LDIM*NDIM)

typedef _Float16 f16;
typedef _Float16 f16x2 __attribute__((ext_vector_type(2)));
typedef _Float16 f16x4 __attribute__((ext_vector_type(4)));
typedef _Float16 f16x8 __attribute__((ext_vector_type(8)));
typedef __fp16   h16x2 __attribute__((ext_vector_type(2)));
typedef float    f32x4 __attribute__((ext_vector_type(4)));

#define SCAL 0.17677669529663687f      // 1/sqrt(32)
#define CEXP -0.011270992135622957f    // -log2(e)/128
#define CPRE 0.2550340490960039f       // SCAL * log2(e)

extern "C" __device__ _Float16 __ocml_exp2_f16(_Float16);  // -> v_exp_f16

__device__ inline f16x2 pkrtz(float a, float b){
  h16x2 r = __builtin_amdgcn_cvt_pkrtz(a, b);
  union { h16x2 h; f16x2 f; } u; u.h = r;
  return u.f;
}

// ---------------- K0b: pack W^T f16 in MFMA-FRAGMENT order ----------------
// wfrag[p][((jt*4+ks)*64 + lane)*8 + e] = W_p[k][col],
//   col = jt*16 + (lane&15), k = ks*32 + (lane>>4)*8 + e.
__global__ __launch_bounds__(256) void k0b_pack(
    const float* __restrict__ Wq, const float* __restrict__ Wk,
    const float* __restrict__ Wv, const float* __restrict__ Wg,
    const float* __restrict__ Wo, f16* __restrict__ w16)
{
  const float* Ws[5] = {Wq, Wk, Wv, Wg, Wo};
  const int tid = blockIdx.x * 256 + threadIdx.x;
  const int p = tid >> 14, rem = tid & 16383;
  const int e = rem & 7, lane = (rem >> 3) & 63, ksjt = rem >> 9;
  const int ks = ksjt & 3, jt = ksjt >> 2;
  const int col = jt*16 + (lane & 15);
  const int k   = ks*32 + (lane >> 4)*8 + e;
  w16[tid] = (f16)Ws[p][k*128 + col];
}

// ---------------- K1: LN + Q/K/V/Gate via MFMA — 32 rows/block, acc[2][8] ----------------
// Half the accumulator tile (64 AGPRs) -> ~174 unified regs -> occupancy cap
// rises 8 -> ~32 waves/CU. Same coalesced LDS staging + frag-ordered weights
// (R16 lesson: never trade coalescing for occupancy; this trades only reuse).
__global__ __launch_bounds__(256, 2) void k1_ln_qkvg(
    const float* __restrict__ z, const float* __restrict__ lng, const float* __restrict__ lnb,
    const f16* __restrict__ w16,
    const float* __restrict__ bq, const float* __restrict__ bk,
    const float* __restrict__ bv, const float* __restrict__ bg,
    f16* __restrict__ qb, f16* __restrict__ kbuf,
    f16* __restrict__ vbuf, f16* __restrict__ gateb)
{
  __shared__ f16 zl[32*128];   // 8 KB
  const int t = threadIdx.x;
  const int w = t >> 6, lane = t & 63;
  const int m = lane & 15, g = lane >> 4;
  const int row0 = blockIdx.x * 32;

  { // LayerNorm: 8 threads/row, 16 elems each -> swizzled f16 LDS
    const int r = t >> 3, part = t & 7;
    const float* zr = z + (size_t)(row0 + r)*DZC + part*16;
    float vals[16];
    float s = 0.f, sq = 0.f;
    #pragma unroll
    for (int i = 0; i < 4; ++i) {
      float4 v4 = reinterpret_cast<const float4*>(zr)[i];
      vals[i*4+0]=v4.x; vals[i*4+1]=v4.y; vals[i*4+2]=v4.z; vals[i*4+3]=v4.w;
      s  += v4.x+v4.y+v4.z+v4.w;
      sq += v4.x*v4.x + v4.y*v4.y + v4.z*v4.z + v4.w*v4.w;
    }
    s  += __shfl_xor(s, 1);  sq += __shfl_xor(sq, 1);
    s  += __shfl_xor(s, 2);  sq += __shfl_xor(sq, 2);
    s  += __shfl_xor(s, 4);  sq += __shfl_xor(sq, 4);
    const float mu  = s * (1.f/DZC);
    const float var = sq * (1.f/DZC) - mu*mu;
    const float rstd = rsqrtf(var + 1e-5f);
    const float* gg = lng + part*16;
    const float* bb = lnb + part*16;
    #pragma unroll
    for (int i = 0; i < 2; ++i) {
      f16x8 o;
      #pragma unroll
      for (int e = 0; e < 8; ++e)
        o[e] = (f16)((vals[i*8+e]-mu)*rstd*gg[i*8+e] + bb[i*8+e]);
      *reinterpret_cast<f16x8*>(zl + r*128 + (((part*2+i) ^ (r&7))*8)) = o;
    }
  }
  __syncthreads();

  const f16* wp = w16 + w*16384;
  f32x4 acc[2][8];
  #pragma unroll
  for (int it=0;it<2;++it)
    #pragma unroll
    for (int jt=0;jt<8;++jt) acc[it][jt] = (f32x4){0.f,0.f,0.f,0.f};

  #pragma unroll
  for (int ks = 0; ks < 4; ++ks) {
    f16x8 af[8];
    #pragma unroll
    for (int jt=0;jt<8;++jt)
      af[jt] = *reinterpret_cast<const f16x8*>(wp + ((jt*4+ks)*64 + lane)*8);
    f16x8 bf[2];
    #pragma unroll
    for (int it=0;it<2;++it)
      bf[it] = *reinterpret_cast<const f16x8*>(zl + (it*16+m)*128 + (((ks*4+g) ^ (m&7))*8));
    #pragma unroll
    for (int it=0;it<2;++it)
      #pragma unroll
      for (int jt=0;jt<8;++jt)
        acc[it][jt] = __builtin_amdgcn_mfma_f32_16x16x32_f16(af[jt], bf[it], acc[it][jt], 0,0,0);
  }

  const float* bsp = (w==0) ? bq : (w==1) ? bk : (w==2) ? bv : bg;
  float4 bias[8];
  #pragma unroll
  for (int jt=0;jt<8;++jt)
    bias[jt] = *reinterpret_cast<const float4*>(bsp + jt*16 + g*4);

  f16* ob = (w==0) ? qb : (w==1) ? kbuf : (w==2) ? vbuf : gateb;
  #pragma unroll
  for (int it=0;it<2;++it) {
    f16* orow = ob + (size_t)(row0 + it*16 + m)*DCC;
    #pragma unroll
    for (int jt=0;jt<8;++jt) {
      f16x4 o;
      #pragma unroll
      for (int r=0;r<4;++r) {
        float v = acc[it][jt][r] + ((const float*)&bias[jt])[r];
        if (w == 3) v = 1.f/(1.f + __expf(-v));
        o[r] = (f16)v;
      }
      *reinterpret_cast<f16x4*>(orow + jt*16 + g*4) = o;
    }
  }
}

// ---------------- K2: fused attention + out-proj; f16 dbuf cfl + packed glue (R18, verified) ----------------
__global__ __launch_bounds__(256, 2) void k2_attn(
    const f16* __restrict__ qb, const f16* __restrict__ kbuf,
    const f16* __restrict__ vbuf, const f16* __restrict__ gateb,
    const float* __restrict__ dist, const f16* __restrict__ wo16,
    const float* __restrict__ bo, float* __restrict__ out)
{
  __shared__ f16 vt[4*32*256];   // 64 KB V^T; reused as zc[128][132] in epilogue
  __shared__ f16 cfl[2][64*64];  // 16 KB f16 coef tiles, double-buffered (buf = rh)
  const int t = threadIdx.x;
  const int w = t >> 6, lane = t & 63;
  const int m = lane & 15, g = lane >> 4;
  const int orig = blockIdx.x;
  const int swz = (orig & 7)*64 + (orig >> 3);   // bijective XCD swizzle (512%8==0)
  const int l = swz >> 1, half = swz & 1;
  const int r0 = half*128;
  const int lrow0 = l*NDIM;

  { // build VT from row-major vbuf
    #pragma unroll
    for (int hh = 0; hh < 4; ++hh) {
      const f16* vr = vbuf + (size_t)(lrow0 + t)*DCC + hh*DHD;
      #pragma unroll
      for (int p = 0; p < 4; ++p) {
        f16x8 v = *reinterpret_cast<const f16x8*>(vr + p*8);
        #pragma unroll
        for (int e = 0; e < 8; ++e) {
          const int c = p*8 + e;
          vt[hh*8192 + c*256 + (((t>>2) ^ (c&15))*4) + (t&3)] = v[e];
        }
      }
    }
  }

  f16x8 aq[8];
  #pragma unroll
  for (int it = 0; it < 8; ++it)
    aq[it] = *reinterpret_cast<const f16x8*>(
        qb + (size_t)(lrow0 + r0 + it*16 + m)*DCC + w*DHD + g*8);

  f32x4 o[8][2];
  float rs[8];
  #pragma unroll
  for (int it = 0; it < 8; ++it) {
    o[it][0] = (f32x4){0.f,0.f,0.f,0.f};
    o[it][1] = (f32x4){0.f,0.f,0.f,0.f};
    rs[it] = 0.f;
  }

  const float* drow = dist + (size_t)l*(NDIM*NDIM);
  const int prow[4] = { (0*256+t) >> 4, (1*256+t) >> 4, (2*256+t) >> 4, (3*256+t) >> 4 };
  const int pf4  = t & 15;

  // prologue: issue stage-0 (jc=0, rh=0) dist loads into regs
  float4 pf[4];
  #pragma unroll
  for (int p = 0; p < 4; ++p)
    pf[p] = *reinterpret_cast<const float4*>(
        drow + (size_t)(r0 + prow[p])*NDIM + pf4*4);

  __syncthreads();   // VT build complete before any wave reads vt

  const f16* vth = vt + w*8192;

  #pragma unroll 1
  for (int jc = 0; jc < 4; ++jc) {
    f16x8 kf[4];
    #pragma unroll
    for (int jt = 0; jt < 4; ++jt)
      kf[jt] = *reinterpret_cast<const f16x8*>(
          kbuf + (size_t)(lrow0 + jc*64 + jt*16 + m)*DCC + w*DHD + g*8);

    f16x8 bvv[2][2];
    #pragma unroll
    for (int kc = 0; kc < 2; ++kc)
      #pragma unroll
      for (int ct = 0; ct < 2; ++ct) {
        const int c = ct*16 + m;
        const f16x4 lo = *reinterpret_cast<const f16x4*>(
            vth + c*256 + (((jc*16 + (2*kc+0)*4 + g) ^ m) * 4));
        const f16x4 hi = *reinterpret_cast<const f16x4*>(
            vth + c*256 + (((jc*16 + (2*kc+1)*4 + g) ^ m) * 4));
        f16x8 bb;
        #pragma unroll
        for (int e = 0; e < 4; ++e) { bb[e] = lo[e]; bb[4+e] = hi[e]; }
        bvv[kc][ct] = bb;
      }

    #pragma unroll
    for (int rh = 0; rh < 2; ++rh) {
      f16* cflc = &cfl[rh][0];   // buffer parity = rh (stage index jc*2+rh)
      { // convert + store this stage's prefetched dist -> f16 cfl
        const float4 dd[4] = {pf[0], pf[1], pf[2], pf[3]};
        #pragma unroll
        for (int p = 0; p < 4; ++p) {
          const int row = prow[p];
          const f16x2 a = pkrtz(CPRE*exp2f(dd[p].x*dd[p].x*CEXP),
                                CPRE*exp2f(dd[p].y*dd[p].y*CEXP));
          const f16x2 b = pkrtz(CPRE*exp2f(dd[p].z*dd[p].z*CEXP),
                                CPRE*exp2f(dd[p].w*dd[p].w*CEXP));
          const f16x4 cf = __builtin_shufflevector(a, b, 0,1,2,3);
          *reinterpret_cast<f16x4*>(cflc + row*64 + ((pf4 ^ (row & 15))*4)) = cf;
        }
      }
      { // issue NEXT stage's loads — in flight through compute
        const int si1 = jc*2 + rh + 1;
        const int sic = (si1 > 7) ? 7 : si1;
        const int jn = sic >> 1, rn = sic & 1;
        #pragma unroll
        for (int p = 0; p < 4; ++p)
          pf[p] = *reinterpret_cast<const float4*>(
              drow + (size_t)(r0 + rn*64 + prow[p])*NDIM + jn*64 + pf4*4);
      }
      __syncthreads();   // single barrier: all stores to cfl[rh] visible

      #pragma unroll
      for (int itl = 0; itl < 4; ++itl) {
        const int it = rh*4 + itl;
        const int lr = itl*16 + m;
        f16x4 cl[4];
        #pragma unroll
        for (int jt = 0; jt < 4; ++jt)
          cl[jt] = *reinterpret_cast<const f16x4*>(
              cflc + lr*64 + (((jt*4 + g) ^ m)*4));

        f32x4 s[4];
        #pragma unroll
        for (int jt = 0; jt < 4; ++jt)
          s[jt] = __builtin_amdgcn_mfma_f32_16x16x32_f16(
              kf[jt], aq[it], (f32x4){0.f,0.f,0.f,0.f}, 0, 0, 0);

        // packed-f16 glue: x = f16(s) * cf; p = exp2(x) in f16 (v_exp_f16)
        f16x4 pkk[4];
        #pragma unroll
        for (int jt = 0; jt < 4; ++jt) {
          const f16x2 sl = pkrtz(s[jt][0], s[jt][1]);
          const f16x2 sh = pkrtz(s[jt][2], s[jt][3]);
          const f16x2 cll = __builtin_shufflevector(cl[jt], cl[jt], 0,1);
          const f16x2 clh = __builtin_shufflevector(cl[jt], cl[jt], 2,3);
          const f16x2 xl = sl * cll;
          const f16x2 xh = sh * clh;
          f16x4 pv;
          pv[0] = __ocml_exp2_f16(xl[0]);
          pv[1] = __ocml_exp2_f16(xl[1]);
          pv[2] = __ocml_exp2_f16(xh[0]);
          pv[3] = __ocml_exp2_f16(xh[1]);
          pkk[jt] = pv;
        }
        { // rowsum: packed f16 tree, f32 accumulate
          const f16x4 ps4 = (pkk[0] + pkk[1]) + (pkk[2] + pkk[3]);
          const f16x2 ps2 = __builtin_shufflevector(ps4, ps4, 0,1)
                          + __builtin_shufflevector(ps4, ps4, 2,3);
          rs[it] += (float)ps2[0] + (float)ps2[1];
        }

        #pragma unroll
        for (int kc = 0; kc < 2; ++kc) {
          const f16x8 ap = __builtin_shufflevector(pkk[2*kc], pkk[2*kc+1],
                                                   0,1,2,3,4,5,6,7);
          o[it][0] = __builtin_amdgcn_mfma_f32_16x16x32_f16(ap, bvv[kc][0], o[it][0], 0, 0, 0);
          o[it][1] = __builtin_amdgcn_mfma_f32_16x16x32_f16(ap, bvv[kc][1], o[it][1], 0, 0, 0);
        }
      }
    }
  }

  float rinv[8];
  #pragma unroll
  for (int it = 0; it < 8; ++it) {
    float v = rs[it];
    v += __shfl_xor(v, 16);
    v += __shfl_xor(v, 32);
    rinv[it] = 1.f / v;
  }

  // ---- fused epilogue: z_com -> LDS, then out = (zc*gate) @ Wo + bo ----
  __syncthreads();   // all waves done reading vt (jc=3 bvv)
  f16* zc = vt;      // [128][132]
  #pragma unroll
  for (int it = 0; it < 8; ++it)
    #pragma unroll
    for (int r = 0; r < 4; ++r) {
      const float rr = __shfl(rinv[it], (lane & 48) + g*4 + r);
      const int lrow = it*16 + g*4 + r;
      #pragma unroll
      for (int ct = 0; ct < 2; ++ct)
        zc[lrow*132 + w*DHD + ct*16 + m] = (f16)(o[it][ct][r] * rr);
    }
  __syncthreads();

  f32x4 acc2[2][8];
  #pragma unroll
  for (int it2=0;it2<2;++it2)
    #pragma unroll
    for (int jt=0;jt<8;++jt) acc2[it2][jt] = (f32x4){0.f,0.f,0.f,0.f};

  #pragma unroll
  for (int ks = 0; ks < 4; ++ks) {
    f16x8 af[8];
    #pragma unroll
    for (int jt=0;jt<8;++jt)
      af[jt] = *reinterpret_cast<const f16x8*>(wo16 + ((jt*4+ks)*64 + lane)*8);
    f16x8 bf[2];
    #pragma unroll
    for (int it2 = 0; it2 < 2; ++it2) {
      const int lrow = w*32 + it2*16 + m;
      const f16x4 b0 = *reinterpret_cast<const f16x4*>(zc + lrow*132 + ks*32 + g*8);
      const f16x4 b1 = *reinterpret_cast<const f16x4*>(zc + lrow*132 + ks*32 + g*8 + 4);
      const f16x8 zf = __builtin_shufflevector(b0, b1, 0,1,2,3,4,5,6,7);
      const f16x8 gf = *reinterpret_cast<const f16x8*>(
          gateb + (size_t)(lrow0 + r0 + lrow)*DCC + ks*32 + g*8);
      bf[it2] = zf * gf;
    }
    #pragma unroll
    for (int it2=0;it2<2;++it2)
      #pragma unroll
      for (int jt=0;jt<8;++jt)
        acc2[it2][jt] = __builtin_amdgcn_mfma_f32_16x16x32_f16(af[jt], bf[it2], acc2[it2][jt], 0,0,0);
  }

  #pragma unroll
  for (int it2 = 0; it2 < 2; ++it2) {
    const size_t grow = (size_t)(lrow0 + r0 + w*32 + it2*16 + m);
    #pragma unroll
    for (int jt = 0; jt < 8; ++jt) {
      const float4 bias = *reinterpret_cast<const float4*>(bo + jt*16 + g*4);
      float4 ov;
      ov.x = acc2[it2][jt][0] + bias.x;
      ov.y = acc2[it2][jt][1] + bias.y;
      ov.z = acc2[it2][jt][2] + bias.z;
      ov.w = acc2[it2][jt][3] + bias.w;
      *reinterpret_cast<float4*>(out + grow*DZC + jt*16 + g*4) = ov;
    }
  }
}

extern "C" void kernel_launch(void* const* d_in, const int* in_sizes, int n_in,
                              void* d_out, int out_size, void* d_ws, size_t ws_size,
                              hipStream_t stream) {
  const float* z    = (const float*)d_in[0];
  const float* dist = (const float*)d_in[1];
  const float* lng  = (const float*)d_in[2];
  const float* lnb  = (const float*)d_in[3];
  const float* Wq   = (const float*)d_in[4];
  const float* bq   = (const float*)d_in[5];
  const float* Wk   = (const float*)d_in[6];
  const float* bk   = (const float*)d_in[7];
  const float* Wv   = (const float*)d_in[8];
  const float* bv   = (const float*)d_in[9];
  const float* Wg   = (const float*)d_in[10];
  const float* bg   = (const float*)d_in[11];
  const float* Wo   = (const float*)d_in[12];
  const float* bo   = (const float*)d_in[13];
  float* out = (float*)d_out;

  const size_t elems = (size_t)MROWS * DCC;  // 8,388,608
  f16* qb    = (f16*)d_ws;
  f16* kbuf  = qb    + elems;
  f16* vbuf  = kbuf  + elems;
  f16* gateb = vbuf  + elems;
  f16* w16   = gateb + elems;   // 5*16384 halves; total ws ≈ 67 MB

  k0b_pack<<<320, 256, 0, stream>>>(Wq, Wk, Wv, Wg, Wo, w16);
  k1_ln_qkvg<<<MROWS/32, 256, 0, stream>>>(z, lng, lnb, w16, bq, bk, bv, bg,
                                           qb, kbuf, vbuf, gateb);
  k2_attn<<<LDIM*2, 256, 0, stream>>>(qb, kbuf, vbuf, gateb, dist,
                                      w16 + 4*16384, bo, out);
}

// Round 21
// 76.855 us; speedup vs baseline: 1.9348x; 1.0635x over previous
//
#include <hip/hip_runtime.h>
#include <hip/hip_fp16.h>

#define LDIM 256
#define NDIM 256
#define DZC  128
#define HN   4
#define DHD  32
#define DCC  128
#define MROWS (LDIM*NDIM)

typedef _Float16 f16;
typedef _Float16 f16x2 __attribute__((ext_vector_type(2)));
typedef _Float16 f16x4 __attribute__((ext_vector_type(4)));
typedef _Float16 f16x8 __attribute__((ext_vector_type(8)));
typedef __fp16   h16x2 __attribute__((ext_vector_type(2)));
typedef float    f32x4 __attribute__((ext_vector_type(4)));

#define SCAL 0.17677669529663687f      // 1/sqrt(32)
#define CEXP -0.011270992135622957f    // -log2(e)/128
#define CPRE 0.2550340490960039f       // SCAL * log2(e)

extern "C" __device__ _Float16 __ocml_exp2_f16(_Float16);  // -> v_exp_f16

__device__ inline f16x2 pkrtz(float a, float b){
  h16x2 r = __builtin_amdgcn_cvt_pkrtz(a, b);
  union { h16x2 h; f16x2 f; } u; u.h = r;
  return u.f;
}

// ---------------- K0b: pack W^T f16 in MFMA-FRAGMENT order ----------------
__global__ __launch_bounds__(256) void k0b_pack(
    const float* __restrict__ Wq, const float* __restrict__ Wk,
    const float* __restrict__ Wv, const float* __restrict__ Wg,
    const float* __restrict__ Wo, f16* __restrict__ w16)
{
  const float* Ws[5] = {Wq, Wk, Wv, Wg, Wo};
  const int tid = blockIdx.x * 256 + threadIdx.x;
  const int p = tid >> 14, rem = tid & 16383;
  const int e = rem & 7, lane = (rem >> 3) & 63, ksjt = rem >> 9;
  const int ks = ksjt & 3, jt = ksjt >> 2;
  const int col = jt*16 + (lane & 15);
  const int k   = ks*32 + (lane >> 4)*8 + e;
  w16[tid] = (f16)Ws[p][k*128 + col];
}

// ---------------- K1: LN + Q/K/V/Gate via MFMA — 32 rows/block + coalesced stores ----------------
// Epilogue v3: acc -> wave-private LDS tile (same-wave DS ordering, no barrier)
// -> 8 x f16x8 stores, each one contiguous 1KB wave transaction (16 full lines),
// vs 32 scattered 8B stores (16 half-line transactions each). R19's occupancy
// null + all-pipes-idle pointed at store-transaction throughput.
__global__ __launch_bounds__(256, 2) void k1_ln_qkvg(
    const float* __restrict__ z, const float* __restrict__ lng, const float* __restrict__ lnb,
    const f16* __restrict__ w16,
    const float* __restrict__ bq, const float* __restrict__ bk,
    const float* __restrict__ bv, const float* __restrict__ bg,
    f16* __restrict__ qb, f16* __restrict__ kbuf,
    f16* __restrict__ vbuf, f16* __restrict__ gateb)
{
  __shared__ f16 sb[4*32*136];   // 34.8 KB: zl (first 8KB) then per-wave transpose tiles
  f16* zl = sb;
  const int t = threadIdx.x;
  const int w = t >> 6, lane = t & 63;
  const int m = lane & 15, g = lane >> 4;
  const int row0 = blockIdx.x * 32;

  { // LayerNorm: 8 threads/row, 16 elems each -> swizzled f16 LDS
    const int r = t >> 3, part = t & 7;
    const float* zr = z + (size_t)(row0 + r)*DZC + part*16;
    float vals[16];
    float s = 0.f, sq = 0.f;
    #pragma unroll
    for (int i = 0; i < 4; ++i) {
      float4 v4 = reinterpret_cast<const float4*>(zr)[i];
      vals[i*4+0]=v4.x; vals[i*4+1]=v4.y; vals[i*4+2]=v4.z; vals[i*4+3]=v4.w;
      s  += v4.x+v4.y+v4.z+v4.w;
      sq += v4.x*v4.x + v4.y*v4.y + v4.z*v4.z + v4.w*v4.w;
    }
    s  += __shfl_xor(s, 1);  sq += __shfl_xor(sq, 1);
    s  += __shfl_xor(s, 2);  sq += __shfl_xor(sq, 2);
    s  += __shfl_xor(s, 4);  sq += __shfl_xor(sq, 4);
    const float mu  = s * (1.f/DZC);
    const float var = sq * (1.f/DZC) - mu*mu;
    const float rstd = rsqrtf(var + 1e-5f);
    const float* gg = lng + part*16;
    const float* bb = lnb + part*16;
    #pragma unroll
    for (int i = 0; i < 2; ++i) {
      f16x8 o;
      #pragma unroll
      for (int e = 0; e < 8; ++e)
        o[e] = (f16)((vals[i*8+e]-mu)*rstd*gg[i*8+e] + bb[i*8+e]);
      *reinterpret_cast<f16x8*>(zl + r*128 + (((part*2+i) ^ (r&7))*8)) = o;
    }
  }
  __syncthreads();

  const f16* wp = w16 + w*16384;
  f32x4 acc[2][8];
  #pragma unroll
  for (int it=0;it<2;++it)
    #pragma unroll
    for (int jt=0;jt<8;++jt) acc[it][jt] = (f32x4){0.f,0.f,0.f,0.f};

  #pragma unroll
  for (int ks = 0; ks < 4; ++ks) {
    f16x8 af[8];
    #pragma unroll
    for (int jt=0;jt<8;++jt)
      af[jt] = *reinterpret_cast<const f16x8*>(wp + ((jt*4+ks)*64 + lane)*8);
    f16x8 bf[2];
    #pragma unroll
    for (int it=0;it<2;++it)
      bf[it] = *reinterpret_cast<const f16x8*>(zl + (it*16+m)*128 + (((ks*4+g) ^ (m&7))*8));
    #pragma unroll
    for (int it=0;it<2;++it)
      #pragma unroll
      for (int jt=0;jt<8;++jt)
        acc[it][jt] = __builtin_amdgcn_mfma_f32_16x16x32_f16(af[jt], bf[it], acc[it][jt], 0,0,0);
  }

  const float* bsp = (w==0) ? bq : (w==1) ? bk : (w==2) ? bv : bg;
  float4 bias[8];
  #pragma unroll
  for (int jt=0;jt<8;++jt)
    bias[jt] = *reinterpret_cast<const float4*>(bsp + jt*16 + g*4);

  __syncthreads();   // all zl reads done before transpose tiles overwrite sb

  f16* tl = sb + w*(32*136);
  #pragma unroll
  for (int it=0;it<2;++it) {
    #pragma unroll
    for (int jt=0;jt<8;++jt) {
      f16x4 o;
      #pragma unroll
      for (int r=0;r<4;++r) {
        float v = acc[it][jt][r] + ((const float*)&bias[jt])[r];
        if (w == 3) v = 1.f/(1.f + __expf(-v));
        o[r] = (f16)v;
      }
      *reinterpret_cast<f16x4*>(tl + (it*16+m)*136 + jt*16 + g*4) = o;
    }
  }
  // same-wave DS ordering: reads below see this wave's writes (no barrier)
  f16* ob = (w==0) ? qb : (w==1) ? kbuf : (w==2) ? vbuf : gateb;
  #pragma unroll
  for (int p = 0; p < 8; ++p) {
    const int rr = p*4 + g, cc = m*8;
    const f16x8 v = *reinterpret_cast<const f16x8*>(tl + rr*136 + cc);
    *reinterpret_cast<f16x8*>(ob + (size_t)(row0 + rr)*DCC + cc) = v;
  }
}

// ---------------- K2: fused attention + out-proj; f16 dbuf cfl + packed glue (R19, verified) ----------------
__global__ __launch_bounds__(256, 2) void k2_attn(
    const f16* __restrict__ qb, const f16* __restrict__ kbuf,
    const f16* __restrict__ vbuf, const f16* __restrict__ gateb,
    const float* __restrict__ dist, const f16* __restrict__ wo16,
    const float* __restrict__ bo, float* __restrict__ out)
{
  __shared__ f16 vt[4*32*256];   // 64 KB V^T; reused as zc[128][132] in epilogue
  __shared__ f16 cfl[2][64*64];  // 16 KB f16 coef tiles, double-buffered (buf = rh)
  const int t = threadIdx.x;
  const int w = t >> 6, lane = t & 63;
  const int m = lane & 15, g = lane >> 4;
  const int orig = blockIdx.x;
  const int swz = (orig & 7)*64 + (orig >> 3);   // bijective XCD swizzle (512%8==0)
  const int l = swz >> 1, half = swz & 1;
  const int r0 = half*128;
  const int lrow0 = l*NDIM;

  { // build VT from row-major vbuf
    #pragma unroll
    for (int hh = 0; hh < 4; ++hh) {
      const f16* vr = vbuf + (size_t)(lrow0 + t)*DCC + hh*DHD;
      #pragma unroll
      for (int p = 0; p < 4; ++p) {
        f16x8 v = *reinterpret_cast<const f16x8*>(vr + p*8);
        #pragma unroll
        for (int e = 0; e < 8; ++e) {
          const int c = p*8 + e;
          vt[hh*8192 + c*256 + (((t>>2) ^ (c&15))*4) + (t&3)] = v[e];
        }
      }
    }
  }

  f16x8 aq[8];
  #pragma unroll
  for (int it = 0; it < 8; ++it)
    aq[it] = *reinterpret_cast<const f16x8*>(
        qb + (size_t)(lrow0 + r0 + it*16 + m)*DCC + w*DHD + g*8);

  f32x4 o[8][2];
  float rs[8];
  #pragma unroll
  for (int it = 0; it < 8; ++it) {
    o[it][0] = (f32x4){0.f,0.f,0.f,0.f};
    o[it][1] = (f32x4){0.f,0.f,0.f,0.f};
    rs[it] = 0.f;
  }

  const float* drow = dist + (size_t)l*(NDIM*NDIM);
  const int prow[4] = { (0*256+t) >> 4, (1*256+t) >> 4, (2*256+t) >> 4, (3*256+t) >> 4 };
  const int pf4  = t & 15;

  // prologue: issue stage-0 (jc=0, rh=0) dist loads into regs
  float4 pf[4];
  #pragma unroll
  for (int p = 0; p < 4; ++p)
    pf[p] = *reinterpret_cast<const float4*>(
        drow + (size_t)(r0 + prow[p])*NDIM + pf4*4);

  __syncthreads();   // VT build complete before any wave reads vt

  const f16* vth = vt + w*8192;

  #pragma unroll 1
  for (int jc = 0; jc < 4; ++jc) {
    f16x8 kf[4];
    #pragma unroll
    for (int jt = 0; jt < 4; ++jt)
      kf[jt] = *reinterpret_cast<const f16x8*>(
          kbuf + (size_t)(lrow0 + jc*64 + jt*16 + m)*DCC + w*DHD + g*8);

    f16x8 bvv[2][2];
    #pragma unroll
    for (int kc = 0; kc < 2; ++kc)
      #pragma unroll
      for (int ct = 0; ct < 2; ++ct) {
        const int c = ct*16 + m;
        const f16x4 lo = *reinterpret_cast<const f16x4*>(
            vth + c*256 + (((jc*16 + (2*kc+0)*4 + g) ^ m) * 4));
        const f16x4 hi = *reinterpret_cast<const f16x4*>(
            vth + c*256 + (((jc*16 + (2*kc+1)*4 + g) ^ m) * 4));
        f16x8 bb;
        #pragma unroll
        for (int e = 0; e < 4; ++e) { bb[e] = lo[e]; bb[4+e] = hi[e]; }
        bvv[kc][ct] = bb;
      }

    #pragma unroll
    for (int rh = 0; rh < 2; ++rh) {
      f16* cflc = &cfl[rh][0];   // buffer parity = rh (stage index jc*2+rh)
      { // convert + store this stage's prefetched dist -> f16 cfl
        const float4 dd[4] = {pf[0], pf[1], pf[2], pf[3]};
        #pragma unroll
        for (int p = 0; p < 4; ++p) {
          const int row = prow[p];
          const f16x2 a = pkrtz(CPRE*exp2f(dd[p].x*dd[p].x*CEXP),
                                CPRE*exp2f(dd[p].y*dd[p].y*CEXP));
          const f16x2 b = pkrtz(CPRE*exp2f(dd[p].z*dd[p].z*CEXP),
                                CPRE*exp2f(dd[p].w*dd[p].w*CEXP));
          const f16x4 cf = __builtin_shufflevector(a, b, 0,1,2,3);
          *reinterpret_cast<f16x4*>(cflc + row*64 + ((pf4 ^ (row & 15))*4)) = cf;
        }
      }
      { // issue NEXT stage's loads — in flight through compute
        const int si1 = jc*2 + rh + 1;
        const int sic = (si1 > 7) ? 7 : si1;
        const int jn = sic >> 1, rn = sic & 1;
        #pragma unroll
        for (int p = 0; p < 4; ++p)
          pf[p] = *reinterpret_cast<const float4*>(
              drow + (size_t)(r0 + rn*64 + prow[p])*NDIM + jn*64 + pf4*4);
      }
      __syncthreads();   // single barrier: all stores to cfl[rh] visible

      #pragma unroll
      for (int itl = 0; itl < 4; ++itl) {
        const int it = rh*4 + itl;
        const int lr = itl*16 + m;
        f16x4 cl[4];
        #pragma unroll
        for (int jt = 0; jt < 4; ++jt)
          cl[jt] = *reinterpret_cast<const f16x4*>(
              cflc + lr*64 + (((jt*4 + g) ^ m)*4));

        f32x4 s[4];
        #pragma unroll
        for (int jt = 0; jt < 4; ++jt)
          s[jt] = __builtin_amdgcn_mfma_f32_16x16x32_f16(
              kf[jt], aq[it], (f32x4){0.f,0.f,0.f,0.f}, 0, 0, 0);

        // packed-f16 glue: x = f16(s) * cf; p = exp2(x) in f16 (v_exp_f16)
        f16x4 pkk[4];
        #pragma unroll
        for (int jt = 0; jt < 4; ++jt) {
          const f16x2 sl = pkrtz(s[jt][0], s[jt][1]);
          const f16x2 sh = pkrtz(s[jt][2], s[jt][3]);
          const f16x2 cll = __builtin_shufflevector(cl[jt], cl[jt], 0,1);
          const f16x2 clh = __builtin_shufflevector(cl[jt], cl[jt], 2,3);
          const f16x2 xl = sl * cll;
          const f16x2 xh = sh * clh;
          f16x4 pv;
          pv[0] = __ocml_exp2_f16(xl[0]);
          pv[1] = __ocml_exp2_f16(xl[1]);
          pv[2] = __ocml_exp2_f16(xh[0]);
          pv[3] = __ocml_exp2_f16(xh[1]);
          pkk[jt] = pv;
        }
        { // rowsum: packed f16 tree, f32 accumulate
          const f16x4 ps4 = (pkk[0] + pkk[1]) + (pkk[2] + pkk[3]);
          const f16x2 ps2 = __builtin_shufflevector(ps4, ps4, 0,1)
                          + __builtin_shufflevector(ps4, ps4, 2,3);
          rs[it] += (float)ps2[0] + (float)ps2[1];
        }

        #pragma unroll
        for (int kc = 0; kc < 2; ++kc) {
          const f16x8 ap = __builtin_shufflevector(pkk[2*kc], pkk[2*kc+1],
                                                   0,1,2,3,4,5,6,7);
          o[it][0] = __builtin_amdgcn_mfma_f32_16x16x32_f16(ap, bvv[kc][0], o[it][0], 0, 0, 0);
          o[it][1] = __builtin_amdgcn_mfma_f32_16x16x32_f16(ap, bvv[kc][1], o[it][1], 0, 0, 0);
        }
      }
    }
  }

  float rinv[8];
  #pragma unroll
  for (int it = 0; it < 8; ++it) {
    float v = rs[it];
    v += __shfl_xor(v, 16);
    v += __shfl_xor(v, 32);
    rinv[it] = 1.f / v;
  }

  // ---- fused epilogue: z_com -> LDS, then out = (zc*gate) @ Wo + bo ----
  __syncthreads();   // all waves done reading vt (jc=3 bvv)
  f16* zc = vt;      // [128][132]
  #pragma unroll
  for (int it = 0; it < 8; ++it)
    #pragma unroll
    for (int r = 0; r < 4; ++r) {
      const float rr = __shfl(rinv[it], (lane & 48) + g*4 + r);
      const int lrow = it*16 + g*4 + r;
      #pragma unroll
      for (int ct = 0; ct < 2; ++ct)
        zc[lrow*132 + w*DHD + ct*16 + m] = (f16)(o[it][ct][r] * rr);
    }
  __syncthreads();

  f32x4 acc2[2][8];
  #pragma unroll
  for (int it2=0;it2<2;++it2)
    #pragma unroll
    for (int jt=0;jt<8;++jt) acc2[it2][jt] = (f32x4){0.f,0.f,0.f,0.f};

  #pragma unroll
  for (int ks = 0; ks < 4; ++ks) {
    f16x8 af[8];
    #pragma unroll
    for (int jt=0;jt<8;++jt)
      af[jt] = *reinterpret_cast<const f16x8*>(wo16 + ((jt*4+ks)*64 + lane)*8);
    f16x8 bf[2];
    #pragma unroll
    for (int it2 = 0; it2 < 2; ++it2) {
      const int lrow = w*32 + it2*16 + m;
      const f16x4 b0 = *reinterpret_cast<const f16x4*>(zc + lrow*132 + ks*32 + g*8);
      const f16x4 b1 = *reinterpret_cast<const f16x4*>(zc + lrow*132 + ks*32 + g*8 + 4);
      const f16x8 zf = __builtin_shufflevector(b0, b1, 0,1,2,3,4,5,6,7);
      const f16x8 gf = *reinterpret_cast<const f16x8*>(
          gateb + (size_t)(lrow0 + r0 + lrow)*DCC + ks*32 + g*8);
      bf[it2] = zf * gf;
    }
    #pragma unroll
    for (int it2=0;it2<2;++it2)
      #pragma unroll
      for (int jt=0;jt<8;++jt)
        acc2[it2][jt] = __builtin_amdgcn_mfma_f32_16x16x32_f16(af[jt], bf[it2], acc2[it2][jt], 0,0,0);
  }

  #pragma unroll
  for (int it2 = 0; it2 < 2; ++it2) {
    const size_t grow = (size_t)(lrow0 + r0 + w*32 + it2*16 + m);
    #pragma unroll
    for (int jt = 0; jt < 8; ++jt) {
      const float4 bias = *reinterpret_cast<const float4*>(bo + jt*16 + g*4);
      float4 ov;
      ov.x = acc2[it2][jt][0] + bias.x;
      ov.y = acc2[it2][jt][1] + bias.y;
      ov.z = acc2[it2][jt][2] + bias.z;
      ov.w = acc2[it2][jt][3] + bias.w;
      *reinterpret_cast<float4*>(out + grow*DZC + jt*16 + g*4) = ov;
    }
  }
}

extern "C" void kernel_launch(void* const* d_in, const int* in_sizes, int n_in,
                              void* d_out, int out_size, void* d_ws, size_t ws_size,
                              hipStream_t stream) {
  const float* z    = (const float*)d_in[0];
  const float* dist = (const float*)d_in[1];
  const float* lng  = (const float*)d_in[2];
  const float* lnb  = (const float*)d_in[3];
  const float* Wq   = (const float*)d_in[4];
  const float* bq   = (const float*)d_in[5];
  const float* Wk   = (const float*)d_in[6];
  const float* bk   = (const float*)d_in[7];
  const float* Wv   = (const float*)d_in[8];
  const float* bv   = (const float*)d_in[9];
  const float* Wg   = (const float*)d_in[10];
  const float* bg   = (const float*)d_in[11];
  const float* Wo   = (const float*)d_in[12];
  const float* bo   = (const float*)d_in[13];
  float* out = (float*)d_out;

  const size_t elems = (size_t)MROWS * DCC;  // 8,388,608
  f16* qb    = (f16*)d_ws;
  f16* kbuf  = qb    + elems;
  f16* vbuf  = kbuf  + elems;
  f16* gateb = vbuf  + elems;
  f16* w16   = gateb + elems;   // 5*16384 halves; total ws ≈ 67 MB

  k0b_pack<<<320, 256, 0, stream>>>(Wq, Wk, Wv, Wg, Wo, w16);
  k1_ln_qkvg<<<MROWS/32, 256, 0, stream>>>(z, lng, lnb, w16, bq, bk, bv, bg,
                                           qb, kbuf, vbuf, gateb);
  k2_attn<<<LDIM*2, 256, 0, stream>>>(qb, kbuf, vbuf, gateb, dist,
                                      w16 + 4*16384, bo, out);
}